// Round 8
// baseline (73.937 us; speedup 1.0000x reference)
//
#include <hip/hip_runtime.h>

typedef __attribute__((ext_vector_type(8))) __bf16 bf16x8;
typedef __attribute__((ext_vector_type(4))) float f32x4;
typedef __attribute__((ext_vector_type(2))) float f32x2;

#define DI   512
#define DO   512
#define XROW (128 * DI)
#define OROW (128 * DO)
#define BK   64
#define NT   8            // 512 / 64 K-tiles

#define LGKM0()  asm volatile("s_waitcnt lgkmcnt(0)" ::: "memory")
#define SBAR()   __builtin_amdgcn_s_barrier()
#define SCHED0() __builtin_amdgcn_sched_barrier(0)

// Both LDS tiles: bf16 [128 rows][64 k] = 128 B/row = 8 x 16B slots.
// Swizzle: slot ^= (row&7)  (byte ^= (row&7)<<4), applied on write AND read.
// Fragment reads (16 consecutive rows, fixed slot) -> 2-way, free (m136).
// A writes (row=t>>2, slots {2c,2c+1}) and B writes (rows 2t+p, slot=wave-
// uniform kq) both spread uniformly across slot classes -> <=2-way.
__device__ __forceinline__ int swz(int row, int kbyte) {
  return (row * 128 + kbyte) ^ ((row & 7) << 4);
}

__global__ __launch_bounds__(512, 4)   // ~95 regs needed < 128 cap: no spill
void nlinear_mfma(const float* __restrict__ xp, const float* __restrict__ wp,
                  const float* __restrict__ bp, float* __restrict__ op) {
  // XCD swizzle: the 8 tiles of one n land on one XCD (nwg=1024, %8==0)
  int blk = blockIdx.x;
  int L  = ((blk & 7) << 7) + (blk >> 3);
  int n  = L >> 3;
  int mt = (L >> 2) & 1;
  int ot = L & 3;
  int mBase = mt << 7;
  int oBase = ot << 7;

  __shared__ __bf16 aT[2][128 * BK];   // 2 x 16 KB
  __shared__ __bf16 bT[2][128 * BK];   // 2 x 16 KB  (64 KB total, 2 blk/CU)

  int tid  = threadIdx.x;
  int lane = tid & 63;
  int wid  = tid >> 6;              // 8 waves: 2m x 4o
  int wm  = (wid >> 2) << 6;
  int wn  = (wid & 3) << 5;
  int l16 = lane & 15;
  int l4  = lane >> 4;

  // A staging: thread t -> m-row t>>2, k-chunk (t&3)*16 (16 consecutive k)
  int am  = tid >> 2;
  int akc = (tid & 3) << 4;
  const float* aSrc = xp + (size_t)(mBase + am) * XROW + n * DI + akc;

  // B staging: thread t -> o-cols {2*(t&63), +1}, k-rows (t>>6)*8..+8
  int bo2 = (tid & 63) << 1;
  int bkq = tid >> 6;               // wave-uniform k-slot
  const float* bSrc = wp + ((size_t)n * DI + (bkq << 3)) * DO + oBase + bo2;

  f32x4 aS[4];
  f32x2 bS[8];

  auto loadA = [&](int kt) {
    #pragma unroll
    for (int i = 0; i < 4; ++i)
      aS[i] = *(const f32x4*)(aSrc + kt * BK + i * 4);
  };
  auto loadB = [&](int kt) {
    #pragma unroll
    for (int j = 0; j < 8; ++j)
      bS[j] = *(const f32x2*)(bSrc + (size_t)(kt * BK + j) * DO);
  };
  auto writeA = [&](int buf) {
    #pragma unroll
    for (int h = 0; h < 2; ++h) {
      bf16x8 v;
      #pragma unroll
      for (int e = 0; e < 8; ++e)
        v[e] = (__bf16)aS[h * 2 + (e >> 2)][e & 3];
      *(bf16x8*)((char*)aT[buf] + swz(am, (akc + h * 8) * 2)) = v;
    }
  };
  auto writeB = [&](int buf) {
    #pragma unroll
    for (int p = 0; p < 2; ++p) {
      bf16x8 v;
      #pragma unroll
      for (int j = 0; j < 8; ++j)
        v[j] = (__bf16)(p ? bS[j].y : bS[j].x);
      *(bf16x8*)((char*)bT[buf] + swz(bo2 + p, bkq * 16)) = v;
    }
  };

  f32x4 acc[4][2];
  #pragma unroll
  for (int i = 0; i < 4; ++i)
    #pragma unroll
    for (int j = 0; j < 2; ++j)
      acc[i][j] = f32x4{0.f, 0.f, 0.f, 0.f};

  auto compute = [&](int buf) {
    #pragma unroll
    for (int ks = 0; ks < 2; ++ks) {
      bf16x8 af[4], bfr[2];
      #pragma unroll
      for (int i = 0; i < 4; ++i)
        af[i] = *(const bf16x8*)((const char*)aT[buf] +
                                 swz(wm + i * 16 + l16, ks * 64 + l4 * 16));
      #pragma unroll
      for (int j = 0; j < 2; ++j)
        bfr[j] = *(const bf16x8*)((const char*)bT[buf] +
                                  swz(wn + j * 16 + l16, ks * 64 + l4 * 16));
      #pragma unroll
      for (int i = 0; i < 4; ++i) {
        acc[i][0] = __builtin_amdgcn_mfma_f32_16x16x32_bf16(af[i], bfr[0], acc[i][0], 0, 0, 0);
        acc[i][1] = __builtin_amdgcn_mfma_f32_16x16x32_bf16(af[i], bfr[1], acc[i][1], 0, 0, 0);
      }
    }
  };

  float bi[2];
  #pragma unroll
  for (int j = 0; j < 2; ++j)
    bi[j] = bp[n * DO + oBase + wn + j * 16 + l16];

  // ---- prologue: buf0 written; tile1 loads in flight ----
  loadA(0); loadB(0);
  writeA(0); writeB(0);       // compiler vmcnt-waits tile0 regs
  loadA(1); loadB(1);         // tile1 in flight across the barrier
  SCHED0();
  LGKM0();
  SBAR();

  // invariant at iter top (post-barrier): buf[cur] complete+visible;
  // regs hold tile kt+1 (in flight or arrived). One barrier per iter.
  for (int kt = 0; kt < NT; ++kt) {
    int cur = kt & 1;
    int nxt = cur ^ 1;
    if (kt + 1 < NT) {
      writeA(nxt);                       // nxt was last read in iter kt-1
      if (kt + 2 < NT) loadA(kt + 2);    // reissue A early (in flight ~1 iter)
      writeB(nxt);
      if (kt + 2 < NT) loadB(kt + 2);
      SCHED0();                          // pin load issue before compute
    }
    compute(cur);
    if (kt + 1 < NT) {
      SCHED0();
      LGKM0();                           // my nxt-writes complete
      SBAR();                            // visible to all; cur free next iter
    }
  }

  // epilogue: D layout col = lane&15, row = (lane>>4)*4 + r (m89-verified)
  #pragma unroll
  for (int i = 0; i < 4; ++i) {
    #pragma unroll
    for (int j = 0; j < 2; ++j) {
      #pragma unroll
      for (int r = 0; r < 4; ++r) {
        int m = mBase + wm + i * 16 + l4 * 4 + r;
        int o = oBase + wn + j * 16 + l16;
        op[(size_t)m * OROW + n * DO + o] = acc[i][j][r] + bi[j];
      }
    }
  }
}

extern "C" void kernel_launch(void* const* d_in, const int* in_sizes, int n_in,
                              void* d_out, int out_size, void* d_ws, size_t ws_size,
                              hipStream_t stream) {
  const float* x = (const float*)d_in[0];
  const float* w = (const float*)d_in[1];
  const float* b = (const float*)d_in[2];
  float* o = (float*)d_out;
  hipLaunchKernelGGL(nlinear_mfma, dim3(1024), dim3(512), 0, stream, x, w, b, o);
}

// Round 9
// 48.406 us; speedup vs baseline: 1.5274x; 1.5274x over previous
//
#include <hip/hip_runtime.h>

typedef __attribute__((ext_vector_type(8))) __bf16 bf16x8;
typedef __attribute__((ext_vector_type(4))) float f32x4;

#define DI 512
#define DO 512
#define XROW (128 * DI)
#define OROW (128 * DO)
#define BK 32
#define BUFSZ 24576     // 16 KB A (fp32 [128][32]) + 8 KB B (bf16 [128][32])
#define BOFF  16384

#define VMCNT(n) asm volatile("s_waitcnt vmcnt(" #n ")" ::: "memory")
#define LGKM0()  asm volatile("s_waitcnt lgkmcnt(0)" ::: "memory")
#define SBAR()   __builtin_amdgcn_s_barrier()
#define SCHED0() __builtin_amdgcn_sched_barrier(0)

__global__ __launch_bounds__(512, 4)
void nlinear_mfma(const float* __restrict__ xp, const float* __restrict__ wp,
                  const float* __restrict__ bp, float* __restrict__ op) {
  // XCD swizzle: 8 tiles of one n -> one XCD (nwg=1024, %8==0)
  int blk = blockIdx.x;
  int L = ((blk & 7) << 7) + (blk >> 3);
  int n = L >> 3, mt = (L >> 2) & 1, ot = L & 3;
  int mBase = mt << 7, oBase = ot << 7;

  extern __shared__ char lds[];     // 3 * 24576 = 72 KB (dynamic: >64KB static cap)

  int tid = threadIdx.x, lane = tid & 63, wid = tid >> 6;
  int wm = (wid >> 2) << 6, wn = (wid & 3) << 5;   // wave tile 64x32
  int l16 = lane & 15, l4 = lane >> 4;

  // A DMA: wave w covers rows w*16..+16, 2 instrs x 1KB; source pre-swizzled
  // slot g = (lane&7) ^ ((row>>1)&7); LDS dest linear (rule #21). R5-verified.
  unsigned aOff[2];
  #pragma unroll
  for (int i = 0; i < 2; ++i) {
    int r0 = (wid << 4) + (i << 3);
    int row = r0 + (lane >> 3);
    int g = (lane & 7) ^ ((row >> 1) & 7);
    aOff[i] = (unsigned)(((mBase + row) * XROW + n * DI) * 4 + g * 16);
  }

  // B staging: thread t -> o-col t&127, k-group t>>7 (8 k scalars, 256B/wave)
  int bo = tid & 127, bkq = tid >> 7;
  const float* bSrc = wp + ((size_t)n * DI + (bkq << 3)) * DO + oBase + bo;
  int bWrByte = BOFF + bo * 64 + ((bkq ^ ((bo >> 1) & 3)) << 4);

  auto gloadA = [&](int bufOff, int kt) {
    #pragma unroll
    for (int i = 0; i < 2; ++i) {
      int r0 = (wid << 4) + (i << 3);
      __builtin_amdgcn_global_load_lds(
          (const __attribute__((address_space(1))) void*)
              ((const char*)xp + aOff[i] + (unsigned)(kt * 128)),
          (__attribute__((address_space(3))) void*)(lds + bufOff + r0 * 128),
          16, 0, 0);
    }
  };
  auto loadB = [&](int kt, float (&r)[8]) {
    #pragma unroll
    for (int j = 0; j < 8; ++j)
      r[j] = bSrc[(size_t)(kt * BK + j) * DO];
  };
  auto writeB = [&](int bufOff, float (&r)[8]) {
    bf16x8 v;
    #pragma unroll
    for (int j = 0; j < 8; ++j) v[j] = (__bf16)r[j];
    *(bf16x8*)(lds + bufOff + bWrByte) = v;
  };

  f32x4 acc[4][2];
  #pragma unroll
  for (int i = 0; i < 4; ++i)
    #pragma unroll
    for (int j = 0; j < 2; ++j)
      acc[i][j] = f32x4{0.f, 0.f, 0.f, 0.f};

  auto compute = [&](int bufOff) {
    bf16x8 bfr[2];
    #pragma unroll
    for (int j = 0; j < 2; ++j) {
      int row = wn + j * 16 + l16;
      int slot = l4 ^ ((row >> 1) & 3);
      bfr[j] = *(const bf16x8*)(lds + bufOff + BOFF + row * 64 + slot * 16);
    }
    #pragma unroll
    for (int i = 0; i < 4; ++i) {
      int row = wm + i * 16 + l16;
      int v7 = (row >> 1) & 7;
      const char* rb = lds + bufOff + row * 128;
      f32x4 lo = *(const f32x4*)(rb + (((2 * l4) ^ v7) << 4));
      f32x4 hi = *(const f32x4*)(rb + (((2 * l4 + 1) ^ v7) << 4));
      bf16x8 a;
      a[0] = (__bf16)lo.x; a[1] = (__bf16)lo.y; a[2] = (__bf16)lo.z; a[3] = (__bf16)lo.w;
      a[4] = (__bf16)hi.x; a[5] = (__bf16)hi.y; a[6] = (__bf16)hi.z; a[7] = (__bf16)hi.w;
      acc[i][0] = __builtin_amdgcn_mfma_f32_16x16x32_bf16(a, bfr[0], acc[i][0], 0, 0, 0);
      acc[i][1] = __builtin_amdgcn_mfma_f32_16x16x32_bf16(a, bfr[1], acc[i][1], 0, 0, 0);
    }
  };

  float bi[2];
  #pragma unroll
  for (int j = 0; j < 2; ++j)
    bi[j] = bp[n * DO + oBase + wn + j * 16 + l16];

  float bR0[8], bR1[8];
  int cOff = 0, wOff = BUFSZ, gOff = 2 * BUFSZ;

  // ---- prologue: buf0 staged; A0,A1 + B1,B2 in flight; A0 retired ----
  gloadA(0, 0);        // A0 -> buf0
  loadB(0, bR0);
  writeB(0, bR0);      // auto-waits B0 (in-order: retires A0 too; one-time)
  loadB(1, bR1);       // B1
  gloadA(BUFSZ, 1);    // A1 (AFTER B1: writeB(1)'s wait must NOT retire A1)
  loadB(2, bR0);       // B2
  SCHED0();
  LGKM0();
  SBAR();
  SCHED0();

  // iter kt: writeB(kt+1)->wOff [auto-vmcnt retires A(kt)]; gloadA(kt+2)->gOff;
  // loadB(kt+3) into the set just freed; compute(cOff); VMCNT(18) retires
  // A(kt+1) [keeps A(kt+2)2 + B(kt+2)8 + B(kt+3)8 = 18 in flight]; barrier.
  #define STEP(KT, BRS, VMLINE, DO_LB, DO_GA)                     \
    {                                                             \
      writeB(wOff, BRS);                                          \
      if (DO_GA) gloadA(gOff, (KT) + 2);                          \
      if (DO_LB) loadB((KT) + 3, BRS);                            \
      compute(cOff);                                              \
      SCHED0();                                                   \
      VMLINE;                                                     \
      LGKM0();                                                    \
      SBAR();                                                     \
      SCHED0();                                                   \
      int _t = cOff; cOff = wOff; wOff = gOff; gOff = _t;         \
    }

  for (int kt = 0; kt < 12; kt += 2) {
    STEP(kt,     bR1, VMCNT(18), true, true);
    STEP(kt + 1, bR0, VMCNT(18), true, true);
  }
  STEP(12, bR1, VMCNT(18), true,  true);    // loads B15, A14
  STEP(13, bR0, VMCNT(2),  false, true);    // loads A15; retire A14, keep A15
  STEP(14, bR1, VMCNT(0),  false, false);   // writeB(15); retire A15
  compute(cOff);                            // iter 15, no sync needed after
  #undef STEP

  // epilogue: D layout col = lane&15, row = (lane>>4)*4 + r (m89-verified)
  #pragma unroll
  for (int i = 0; i < 4; ++i) {
    #pragma unroll
    for (int j = 0; j < 2; ++j) {
      #pragma unroll
      for (int r = 0; r < 4; ++r) {
        int m = mBase + wm + i * 16 + l4 * 4 + r;
        int o = oBase + wn + j * 16 + l16;
        op[(size_t)m * OROW + n * DO + o] = acc[i][j][r] + bi[j];
      }
    }
  }
}

extern "C" void kernel_launch(void* const* d_in, const int* in_sizes, int n_in,
                              void* d_out, int out_size, void* d_ws, size_t ws_size,
                              hipStream_t stream) {
  const float* x = (const float*)d_in[0];
  const float* w = (const float*)d_in[1];
  const float* b = (const float*)d_in[2];
  float* o = (float*)d_out;
  hipLaunchKernelGGL(nlinear_mfma, dim3(1024), dim3(512), 3 * BUFSZ, stream,
                     x, w, b, o);
}

// Round 10
// 48.031 us; speedup vs baseline: 1.5394x; 1.0078x over previous
//
#include <hip/hip_runtime.h>

typedef __attribute__((ext_vector_type(8))) __bf16 bf16x8;
typedef __attribute__((ext_vector_type(4))) float f32x4;

#define DI 512
#define DO 512
#define XROW (128 * DI)
#define OROW (128 * DO)
#define BK 32
#define BOFF 16384          // A: fp32 [128][32] = 16 KB | B: bf16 [256][32] = 16 KB
#define BUFSZ 32768

#define VMCNT(n) asm volatile("s_waitcnt vmcnt(" #n ")" ::: "memory")
#define LGKM0()  asm volatile("s_waitcnt lgkmcnt(0)" ::: "memory")
#define SBAR()   __builtin_amdgcn_s_barrier()
#define SCHED0() __builtin_amdgcn_sched_barrier(0)

__global__ __launch_bounds__(512, 4)
void nlinear_mfma(const float* __restrict__ xp, const float* __restrict__ wp,
                  const float* __restrict__ bp, float* __restrict__ op) {
  // XCD swizzle: 512 blocks, 64 per XCD; the 4 tiles of one n stay together
  int blk = blockIdx.x;
  int L = ((blk & 7) << 6) + (blk >> 3);
  int n = L >> 2, mt = (L >> 1) & 1, ot = L & 1;
  int mBase = mt << 7, oBase = ot << 8;      // block tile: 128m x 256o

  __shared__ char lds[2 * BUFSZ];            // 64 KB

  int tid = threadIdx.x, lane = tid & 63, wid = tid >> 6;
  int wm = (wid >> 2) << 6, wn = (wid & 3) << 6;   // wave tile 64m x 64o
  int l16 = lane & 15, l4 = lane >> 4;

  // A DMA (R8-proven): wave w rows w*16..+16, 2 instrs x 1KB; source pre-
  // swizzled slot g = (lane&7) ^ ((row>>1)&7), LDS dest linear (rule #21).
  unsigned aOff[2];
  #pragma unroll
  for (int i = 0; i < 2; ++i) {
    int r0 = (wid << 4) + (i << 3);
    int row = r0 + (lane >> 3);
    int g = (lane & 7) ^ ((row >> 1) & 7);
    aOff[i] = (unsigned)(((mBase + row) * XROW + n * DI) * 4 + g * 16);
  }
  auto gloadA = [&](int bufOff, int kt) {
    #pragma unroll
    for (int i = 0; i < 2; ++i) {
      int r0 = (wid << 4) + (i << 3);
      __builtin_amdgcn_global_load_lds(
          (const __attribute__((address_space(1))) void*)
              ((const char*)xp + aOff[i] + (unsigned)(kt * 128)),
          (__attribute__((address_space(3))) void*)(lds + bufOff + r0 * 128),
          16, 0, 0);
    }
  };

  // B staging: thread t -> o-col t&255, k-half (t>>8)*16 : 16 scalars,
  // each load wave-contiguous (256 consecutive floats per k-row).
  int bo = tid & 255, kh = tid >> 8;          // kh wave-uniform
  const float* bSrc = wp + ((size_t)n * DI + (kh << 4)) * DO + oBase + bo;
  int bWr0 = BOFF + bo * 64 + ((((kh << 1))     ^ ((bo >> 1) & 3)) << 4);
  int bWr1 = BOFF + bo * 64 + ((((kh << 1) | 1) ^ ((bo >> 1) & 3)) << 4);

  float bR[16];
  auto loadB = [&](int kt) {
    #pragma unroll
    for (int r = 0; r < 16; ++r)
      bR[r] = bSrc[(size_t)(kt * BK + r) * DO];
  };
  auto writeB = [&](int bufOff) {
    bf16x8 v0, v1;
    #pragma unroll
    for (int r = 0; r < 8; ++r) { v0[r] = (__bf16)bR[r]; v1[r] = (__bf16)bR[8 + r]; }
    *(bf16x8*)(lds + bufOff + bWr0) = v0;
    *(bf16x8*)(lds + bufOff + bWr1) = v1;
  };

  f32x4 acc[4][4];
  #pragma unroll
  for (int i = 0; i < 4; ++i)
    #pragma unroll
    for (int j = 0; j < 4; ++j)
      acc[i][j] = f32x4{0.f, 0.f, 0.f, 0.f};

  auto compute = [&](int bufOff) {
    bf16x8 af[4];
    #pragma unroll
    for (int i = 0; i < 4; ++i) {           // A frag: fp32 lo/hi -> cvt (16 pk)
      int row = wm + i * 16 + l16;
      int v7 = (row >> 1) & 7;
      const char* rb = lds + bufOff + row * 128;
      f32x4 lo = *(const f32x4*)(rb + ((((l4 << 1))     ^ v7) << 4));
      f32x4 hi = *(const f32x4*)(rb + ((((l4 << 1) | 1) ^ v7) << 4));
      af[i][0] = (__bf16)lo.x; af[i][1] = (__bf16)lo.y;
      af[i][2] = (__bf16)lo.z; af[i][3] = (__bf16)lo.w;
      af[i][4] = (__bf16)hi.x; af[i][5] = (__bf16)hi.y;
      af[i][6] = (__bf16)hi.z; af[i][7] = (__bf16)hi.w;
    }
    #pragma unroll
    for (int j = 0; j < 4; ++j) {           // B frag transient: amortize af
      int row = wn + j * 16 + l16;
      int slot = l4 ^ ((row >> 1) & 3);
      bf16x8 bfr = *(const bf16x8*)(lds + bufOff + BOFF + row * 64 + slot * 16);
      #pragma unroll
      for (int i = 0; i < 4; ++i)
        acc[i][j] = __builtin_amdgcn_mfma_f32_16x16x32_bf16(af[i], bfr, acc[i][j], 0, 0, 0);
    }
  };

  float bi[4];
  #pragma unroll
  for (int j = 0; j < 4; ++j)
    bi[j] = bp[n * DO + oBase + wn + j * 16 + l16];

  // ---- prologue: buf0 staged; B1 in flight ----
  gloadA(0, 0);            // A0 (2 VMEM, oldest)
  loadB(0);                // B0 (16 VMEM)
  writeB(0);               // waits B0 -> retires A0 too (in-order)
  loadB(1);                // B1 in flight across barrier
  SCHED0(); LGKM0(); SBAR(); SCHED0();

  // iter kt: stage tile kt+1 into nxt, compute cur; VMCNT(16) retires
  // A(kt+1) (keeps B(kt+2)'s 16 in flight). One barrier per iter.
  for (int kt = 0; kt < 14; ++kt) {
    int curOff = (kt & 1) * BUFSZ, nxtOff = curOff ^ BUFSZ;
    writeB(nxtOff);        // B(kt+1): compiler-waits its 16 loads
    gloadA(nxtOff, kt + 1);
    loadB(kt + 2);
    compute(curOff);
    SCHED0();
    VMCNT(16);
    LGKM0(); SBAR(); SCHED0();
  }
  // kt=14: no more B to load
  writeB(BUFSZ);           // B15 -> buf1
  gloadA(BUFSZ, 15);       // A15
  compute(0);
  SCHED0();
  VMCNT(0);
  LGKM0(); SBAR(); SCHED0();
  compute(BUFSZ);          // kt=15

  // epilogue: D layout col = lane&15, row = (lane>>4)*4 + r (m89-verified)
  #pragma unroll
  for (int i = 0; i < 4; ++i) {
    #pragma unroll
    for (int j = 0; j < 4; ++j) {
      #pragma unroll
      for (int r = 0; r < 4; ++r) {
        int m = mBase + wm + i * 16 + l4 * 4 + r;
        int o = oBase + wn + j * 16 + l16;
        op[(size_t)m * OROW + n * DO + o] = acc[i][j][r] + bi[j];
      }
    }
  }
}

extern "C" void kernel_launch(void* const* d_in, const int* in_sizes, int n_in,
                              void* d_out, int out_size, void* d_ws, size_t ws_size,
                              hipStream_t stream) {
  const float* x = (const float*)d_in[0];
  const float* w = (const float*)d_in[1];
  const float* b = (const float*)d_in[2];
  float* o = (float*)d_out;
  hipLaunchKernelGGL(nlinear_mfma, dim3(512), dim3(512), 0, stream, x, w, b, o);
}

// Round 11
// 45.505 us; speedup vs baseline: 1.6248x; 1.0555x over previous
//
#include <hip/hip_runtime.h>

typedef __attribute__((ext_vector_type(8))) __bf16 bf16x8;
typedef __attribute__((ext_vector_type(4))) float f32x4;
typedef __attribute__((ext_vector_type(2))) float f32x2;

#define DI 512
#define DO 512
#define XROW (128 * DI)
#define OROW (128 * DO)
#define BK 32
#define BOFF 16384          // A: fp32 [128][32] = 16 KB | B: bf16 [256][32] = 16 KB
#define BUFSZ 32768

#define VMCNT(n) asm volatile("s_waitcnt vmcnt(" #n ")" ::: "memory")
#define LGKM0()  asm volatile("s_waitcnt lgkmcnt(0)" ::: "memory")
#define SBAR()   __builtin_amdgcn_s_barrier()
#define SCHED0() __builtin_amdgcn_sched_barrier(0)

__global__ __launch_bounds__(512, 4)
void nlinear_mfma(const float* __restrict__ xp, const float* __restrict__ wp,
                  const float* __restrict__ bp, float* __restrict__ op) {
  // XCD swizzle: 512 blocks, 64 per XCD; the 4 tiles of one n stay together
  int blk = blockIdx.x;
  int L = ((blk & 7) << 6) + (blk >> 3);
  int n = L >> 2, mt = (L >> 1) & 1, ot = L & 1;
  int mBase = mt << 7, oBase = ot << 8;      // block tile: 128m x 256o

  __shared__ char lds[2 * BUFSZ];            // 64 KB

  int tid = threadIdx.x, lane = tid & 63, wid = tid >> 6;
  int wm = (wid >> 2) << 6, wn = (wid & 3) << 6;   // wave tile 64m x 64o
  int l16 = lane & 15, l4 = lane >> 4;

  // A DMA (R8/R9-proven): wave w rows w*16..+16, 2 instrs x 1KB; source
  // pre-swizzled slot g = (lane&7) ^ ((row>>1)&7), LDS dest linear (rule #21).
  unsigned aOff[2];
  #pragma unroll
  for (int i = 0; i < 2; ++i) {
    int r0 = (wid << 4) + (i << 3);
    int row = r0 + (lane >> 3);
    int g = (lane & 7) ^ ((row >> 1) & 7);
    aOff[i] = (unsigned)(((mBase + row) * XROW + n * DI) * 4 + g * 16);
  }
  auto gloadA = [&](int bufOff, int kt) {
    #pragma unroll
    for (int i = 0; i < 2; ++i) {
      int r0 = (wid << 4) + (i << 3);
      __builtin_amdgcn_global_load_lds(
          (const __attribute__((address_space(1))) void*)
              ((const char*)xp + aOff[i] + (unsigned)(kt * 128)),
          (__attribute__((address_space(3))) void*)(lds + bufOff + r0 * 128),
          16, 0, 0);
    }
  };

  // B staging (vectorized, R3-style): thread t -> o-pair {2*(t&127), +1},
  // k-range kq*8..+8. 8 x f32x2 loads (512B/wave contiguous per k-row),
  // 2 x b128 k-contiguous writes.
  // B LDS: [256 o][32 k] bf16, 64B/row = 4 slots; slot16 = (k>>3)^((o>>1)&3).
  int bo2 = (tid & 127) << 1, kq = tid >> 7;       // kq wave-uniform 0..3
  const float* bSrc = wp + ((size_t)n * DI + (kq << 3)) * DO + oBase + bo2;
  int bWr0 = BOFF + (bo2)     * 64 + ((kq ^ ((bo2 >> 1) & 3)) << 4);
  int bWr1 = BOFF + (bo2 + 1) * 64 + ((kq ^ ((bo2 >> 1) & 3)) << 4);

  f32x2 bRv[8];
  auto loadB = [&](int kt) {
    #pragma unroll
    for (int j = 0; j < 8; ++j)
      bRv[j] = *(const f32x2*)(bSrc + (size_t)(kt * BK + j) * DO);
  };
  auto writeB = [&](int bufOff) {
    bf16x8 v0, v1;
    #pragma unroll
    for (int j = 0; j < 8; ++j) { v0[j] = (__bf16)bRv[j].x; v1[j] = (__bf16)bRv[j].y; }
    *(bf16x8*)(lds + bufOff + bWr0) = v0;
    *(bf16x8*)(lds + bufOff + bWr1) = v1;
  };

  f32x4 acc[4][4];
  #pragma unroll
  for (int i = 0; i < 4; ++i)
    #pragma unroll
    for (int j = 0; j < 4; ++j)
      acc[i][j] = f32x4{0.f, 0.f, 0.f, 0.f};

  bf16x8 af[4];
  auto loadAfrags = [&](int bufOff) {
    #pragma unroll
    for (int i = 0; i < 4; ++i) {
      int row = wm + i * 16 + l16;
      int v7 = (row >> 1) & 7;
      const char* rb = lds + bufOff + row * 128;
      f32x4 lo = *(const f32x4*)(rb + ((((l4 << 1))     ^ v7) << 4));
      f32x4 hi = *(const f32x4*)(rb + ((((l4 << 1) | 1) ^ v7) << 4));
      af[i][0] = (__bf16)lo.x; af[i][1] = (__bf16)lo.y;
      af[i][2] = (__bf16)lo.z; af[i][3] = (__bf16)lo.w;
      af[i][4] = (__bf16)hi.x; af[i][5] = (__bf16)hi.y;
      af[i][6] = (__bf16)hi.z; af[i][7] = (__bf16)hi.w;
    }
  };
  auto computeJ = [&](int bufOff, int j) {
    int row = wn + j * 16 + l16;
    int slot = l4 ^ ((row >> 1) & 3);
    bf16x8 bfr = *(const bf16x8*)(lds + bufOff + BOFF + row * 64 + slot * 16);
    #pragma unroll
    for (int i = 0; i < 4; ++i)
      acc[i][j] = __builtin_amdgcn_mfma_f32_16x16x32_bf16(af[i], bfr, acc[i][j], 0, 0, 0);
  };

  float bi[4];
  #pragma unroll
  for (int j = 0; j < 4; ++j)
    bi[j] = bp[n * DO + oBase + wn + j * 16 + l16];

  // ---- prologue: buf0 staged; B1 in flight across the barrier ----
  gloadA(0, 0);            // A0 (oldest)
  loadB(0);
  writeB(0);               // waits B0 regs -> in-order retires A0 too
  loadB(1);
  SCHED0(); LGKM0(); SBAR(); SCHED0();

  // iter kt: J0,J1 from cur; stage tile kt+1 (A-DMA + B-write) + issue
  // B(kt+2); J2,J3; VMCNT(8) retires A(kt+1), keeps B(kt+2) in flight.
  for (int kt = 0; kt < 14; ++kt) {
    int curOff = (kt & 1) * BUFSZ, nxtOff = curOff ^ BUFSZ;
    loadAfrags(curOff);
    computeJ(curOff, 0);
    computeJ(curOff, 1);
    gloadA(nxtOff, kt + 1);  // issue early: full half-iter to land
    writeB(nxtOff);          // B(kt+1) regs aged ~1 iter
    loadB(kt + 2);
    SCHED0();
    computeJ(curOff, 2);
    computeJ(curOff, 3);
    SCHED0();
    VMCNT(8);
    LGKM0(); SBAR(); SCHED0();
  }
  // kt=14: stage tile 15, no more B loads
  {
    loadAfrags(0);
    computeJ(0, 0); computeJ(0, 1);
    gloadA(BUFSZ, 15);
    writeB(BUFSZ);
    SCHED0();
    computeJ(0, 2); computeJ(0, 3);
    SCHED0();
    VMCNT(0);
    LGKM0(); SBAR(); SCHED0();
  }
  // kt=15
  loadAfrags(BUFSZ);
  computeJ(BUFSZ, 0); computeJ(BUFSZ, 1);
  computeJ(BUFSZ, 2); computeJ(BUFSZ, 3);

  // epilogue: D layout col = lane&15, row = (lane>>4)*4 + r (m89-verified)
  #pragma unroll
  for (int i = 0; i < 4; ++i) {
    #pragma unroll
    for (int j = 0; j < 4; ++j) {
      #pragma unroll
      for (int r = 0; r < 4; ++r) {
        int m = mBase + wm + i * 16 + l4 * 4 + r;
        int o = oBase + wn + j * 16 + l16;
        op[(size_t)m * OROW + n * DO + o] = acc[i][j][r] + bi[j];
      }
    }
  }
}

extern "C" void kernel_launch(void* const* d_in, const int* in_sizes, int n_in,
                              void* d_out, int out_size, void* d_ws, size_t ws_size,
                              hipStream_t stream) {
  const float* x = (const float*)d_in[0];
  const float* w = (const float*)d_in[1];
  const float* b = (const float*)d_in[2];
  float* o = (float*)d_out;
  hipLaunchKernelGGL(nlinear_mfma, dim3(512), dim3(512), 0, stream, x, w, b, o);
}